// Round 1
// baseline (10.891 us; speedup 1.0000x reference)
//
#include <hip/hip_runtime.h>

#define BATCH 1024
#define FEAT_DIM 128
#define NUM_CLASSES 100000

// Each 64-lane wave computes one row's squared distance to its labeled center.
// block = 256 threads = 4 waves -> grid = BATCH/4 = 256 blocks.
__global__ void centerloss_rowdist(const float* __restrict__ x,
                                   const int* __restrict__ labels,
                                   const float* __restrict__ centers,
                                   float* __restrict__ rowsq) {
    const int wave = threadIdx.x >> 6;           // 0..3
    const int lane = threadIdx.x & 63;           // 0..63
    const int row  = blockIdx.x * 4 + wave;      // 0..1023

    const long long lbl = (long long)labels[row];

    // 64 lanes x float2 = 128 floats = one full row (coalesced 8B/lane)
    const float2* xr = reinterpret_cast<const float2*>(x + (long long)row * FEAT_DIM);
    const float2* cr = reinterpret_cast<const float2*>(centers + lbl * FEAT_DIM);

    const float2 xa = xr[lane];
    const float2 ca = cr[lane];
    const float dx = xa.x - ca.x;
    const float dy = xa.y - ca.y;
    float s = dx * dx + dy * dy;

    // wave64 shuffle reduction (fixed order -> deterministic)
    #pragma unroll
    for (int o = 32; o > 0; o >>= 1)
        s += __shfl_down(s, o, 64);

    if (lane == 0)
        rowsq[row] = s;
}

// Single block reduces the 1024 partials in a fixed order and scales.
__global__ void centerloss_finalsum(const float* __restrict__ rowsq,
                                    float* __restrict__ out) {
    const int t = threadIdx.x;                   // 256 threads
    const float4 v = reinterpret_cast<const float4*>(rowsq)[t];
    float s = (v.x + v.y) + (v.z + v.w);

    #pragma unroll
    for (int o = 32; o > 0; o >>= 1)
        s += __shfl_down(s, o, 64);

    __shared__ float ws[4];
    if ((t & 63) == 0)
        ws[t >> 6] = s;
    __syncthreads();

    if (t == 0) {
        const float tot = (ws[0] + ws[1]) + (ws[2] + ws[3]);
        // mean over the full B*C matrix, exactly as torch .mean()
        *out = tot * (1.0f / ((float)BATCH * (float)NUM_CLASSES));
    }
}

extern "C" void kernel_launch(void* const* d_in, const int* in_sizes, int n_in,
                              void* d_out, int out_size, void* d_ws, size_t ws_size,
                              hipStream_t stream) {
    const float* x       = (const float*)d_in[0];
    const int*   labels  = (const int*)d_in[1];
    const float* centers = (const float*)d_in[2];
    float*       out     = (float*)d_out;
    float*       rowsq   = (float*)d_ws;   // 1024 floats = 4 KB scratch

    centerloss_rowdist<<<BATCH / 4, 256, 0, stream>>>(x, labels, centers, rowsq);
    centerloss_finalsum<<<1, 256, 0, stream>>>(rowsq, out);
}